// Round 5
// baseline (354.830 us; speedup 1.0000x reference)
//
#include <hip/hip_runtime.h>
#include <hip/hip_bf16.h>
#include <cstddef>
#include <cstdint>

#define B_ 2
#define D_ 12
#define H_ 200
#define W_ 200
#define HW_ (H_ * W_)
#define DHW_ (D_ * H_ * W_)
#define CELLS_ (B_ * D_ * H_ * W_)   // 960000
#define N_ 60000
#define CIN_ 2
#define COUT_ 64
#define K27 27
#define EPS_ 1e-5f
#define ZCHUNK 6                      // z-planes per wave (12 % 6 == 0)

// ---------------------------------------------------------------------------
// Kernel A: dense cell -> point_id map. scatter[13][n] is the identity tap
// (fz,fy,fx)=(1,1,1) = point n's own cell, always in-bounds. map pre-set to
// -1 via memset(0xFF).
// ---------------------------------------------------------------------------
__global__ void fill_map_kernel(const int* __restrict__ scatter,
                                int* __restrict__ map) {
    int n = blockIdx.x * blockDim.x + threadIdx.x;
    if (n >= N_) return;
    map[scatter[13 * N_ + n]] = n;
}

// ---------------------------------------------------------------------------
// DPP 16-lane allreduce-add (VALU pipe, no LDS). ctrl is a template const.
// After this, every lane of each 16-lane row holds that row's sum.
// ---------------------------------------------------------------------------
template <int CTRL>
__device__ __forceinline__ float dpp_add(float v) {
    int t = __builtin_amdgcn_update_dpp(
        0, __float_as_int(v), CTRL, 0xF, 0xF, true);
    return v + __int_as_float(t);
}
__device__ __forceinline__ float row16_allreduce_add(float v) {
    v = dpp_add<0x140>(v);  // row_mirror       i <-> 15-i
    v = dpp_add<0x141>(v);  // row_half_mirror
    v = dpp_add<0x4E>(v);   // quad_perm i <-> i^2
    v = dpp_add<0xB1>(v);   // quad_perm i <-> i^1
    return v;
}
__device__ __forceinline__ float readlane_f(float v, int l) {
    return __int_as_float(__builtin_amdgcn_readlane(__float_as_int(v), l));
}

// ---------------------------------------------------------------------------
// Kernel B (round-5 rewrite): WAVE-PER-CELL. 64 lanes = 64 output channels.
// Theory: previous 16-lane/cell layout was bound on TA/L1 transaction count
// (group-divergent weight loads split into ~16 lines each). Here the hit
// mask is wave-uniform (single ballot over the 27 probe lanes), so:
//   - hit loop is scalar-driven (SALU branch, no divergence)
//   - weight loads are uniform-base + lane*4: 4 lines instead of 16
//   - feature load is one broadcast line instead of ~16 scattered
//   - LN is a full-wave reduce: 4 DPP row-adds + 4 readlanes, no LDS
// Transactions per cell drop ~48 -> ~30 cy of CU mem-pipe occupancy.
// ---------------------------------------------------------------------------
__global__ __launch_bounds__(256) void gather_wavecell_kernel(
        const float* __restrict__ feat,
        const float* __restrict__ weight,
        const float* __restrict__ gamma,
        const float* __restrict__ beta,
        const int* __restrict__ map,
        float* __restrict__ out) {
    const int tid  = threadIdx.x;
    const int lane = tid & 63;
    const int wid  = tid >> 6;                    // wave in block, 0..3
    const int col  = blockIdx.x * 4 + wid;        // (x,y) column, 0..39999
    const int x = col % W_;
    const int y = col / W_;
    const int bz0 = blockIdx.y * ZCHUNK;          // first bz of chunk
    const int b   = bz0 >= D_ ? 1 : 0;            // chunk never straddles b
    const int z0  = bz0 - b * D_;

    // probe tap decomposition for lanes 0..26 (loop-invariant)
    const int fz = lane / 9, t = lane - fz * 9;
    const int fy = t / 3,    fx = t - fy * 3;
    const int py = y + fy - 1, px = x + fx - 1;
    const bool xy_ok = (lane < K27) && py >= 0 && py < H_ &&
                       px >= 0 && px < W_;

    // per-lane channel params (1 float each), loop-invariant
    const float gmv = gamma[lane];
    const float btv = beta[lane];

    for (int j = 0; j < ZCHUNK; ++j) {
        const int z  = z0 + j;
        const int bz = bz0 + j;

        // ---- probe: one load instruction, lanes 0..26 ----
        int n = -1;
        {
            int pz = z + fz - 1;
            if (xy_ok && pz >= 0 && pz < D_)
                n = map[((b * D_ + pz) * H_ + py) * W_ + px];
        }
        unsigned long long m = __ballot(n >= 0);  // wave-uniform 27-bit mask
        const bool active = (m != 0ull);

        // ---- gather-conv: scalar-driven loop over hits, l wave-uniform ----
        float acc = 0.f;
        while (m) {
            int l = __ffsll(m) - 1;               // tap index == weight k
            m &= m - 1;
            int nn = __builtin_amdgcn_readlane(n, l);   // point id, uniform
            float2 fv = *reinterpret_cast<const float2*>(
                            feat + (size_t)nn * CIN_);  // 1 broadcast line
            const float* wk = weight + l * (CIN_ * COUT_);
            float w0 = wk[lane];                  // 256 B coalesced, 4 lines
            float w1 = wk[COUT_ + lane];
            acc = fmaf(fv.x, w0, acc);
            acc = fmaf(fv.y, w1, acc);
        }

        // ---- LayerNorm across the wave (64 channels = 64 lanes) ----
        float s  = row16_allreduce_add(acc);
        float s2 = row16_allreduce_add(acc * acc);
        float S  = readlane_f(s, 0)  + readlane_f(s, 16)
                 + readlane_f(s, 32) + readlane_f(s, 48);
        float S2 = readlane_f(s2, 0)  + readlane_f(s2, 16)
                 + readlane_f(s2, 32) + readlane_f(s2, 48);
        float mu  = S * (1.0f / COUT_);
        float var = S2 * (1.0f / COUT_) - mu * mu;
        float inv = rsqrtf(var + EPS_);

        float r = active ? fmaxf((acc - mu) * inv * gmv + btv, 0.0f) : 0.0f;

        size_t obase = ((size_t)((bz * H_ + y) * W_ + x)) * COUT_ + lane;
        // nontemporal: output is write-once, never re-read
        __builtin_nontemporal_store(r, out + obase);
    }
}

extern "C" void kernel_launch(void* const* d_in, const int* in_sizes, int n_in,
                              void* d_out, int out_size, void* d_ws, size_t ws_size,
                              hipStream_t stream) {
    const float* feat    = (const float*)d_in[0];   // (N, 2)
    const float* weight  = (const float*)d_in[1];   // (27, 2, 64)
    const float* gamma   = (const float*)d_in[2];   // (64,)
    const float* beta    = (const float*)d_in[3];   // (64,)
    const int*   scatter = (const int*)d_in[4];     // (27, N)
    float* out = (float*)d_out;                     // (CELLS, 64)

    int* map = (int*)d_ws;                          // CELLS * 4 B = 3.84 MB

    (void)hipMemsetAsync(map, 0xFF, (size_t)CELLS_ * sizeof(int), stream);
    {
        int block = 256;
        int grid = (N_ + block - 1) / block;
        fill_map_kernel<<<grid, block, 0, stream>>>(scatter, map);
    }

    // fused gather-conv + LN + ReLU: 1 wave per cell, ZCHUNK z-planes/wave
    {
        dim3 block(256, 1, 1);                      // 4 waves
        dim3 grid((W_ * H_) / 4, (B_ * D_) / ZCHUNK, 1);  // 10000 x 4
        gather_wavecell_kernel<<<grid, block, 0, stream>>>(feat, weight, gamma,
                                                           beta, map, out);
    }
}